// Round 6
// baseline (384.745 us; speedup 1.0000x reference)
//
#include <hip/hip_runtime.h>

typedef unsigned short u16;
typedef __attribute__((ext_vector_type(8))) short bf16x8;   // 8 bf16 = 4 VGPR
typedef __attribute__((ext_vector_type(4))) float f32x4;

#define BATCH 16
#define SEQ   2048
#define EMBD  512
#define NOUT  8
#define QB    64
#define KVB   32
#define NT    (SEQ/KVB)      // 64 KV tiles

#define GLOBAL_AS __attribute__((address_space(1)))
#define LDS_AS    __attribute__((address_space(3)))

__device__ __forceinline__ u16 f2bf(float f){          // f32 -> bf16 RNE
  unsigned u = __float_as_uint(f);
  u += 0x7fffu + ((u >> 16) & 1u);
  return (u16)(u >> 16);
}

__device__ __forceinline__ void gload_lds16(const void* g, void* l){
  __builtin_amdgcn_global_load_lds((const GLOBAL_AS unsigned int*)g,
                                   (LDS_AS unsigned int*)l, 16, 0, 0);
}

// Raw-barrier sync (HK pattern): drain ONLY what the next phase needs.
// BAR_LGKM: LDS-producer -> consumer barrier; K-stage DMA stays in flight.
// BAR_ALL : tile-top barrier; vmcnt(0) is zero-cost (DMA had a full tile).
#define BAR_LGKM() do{ asm volatile("s_waitcnt lgkmcnt(0)" ::: "memory");   \
  __builtin_amdgcn_s_barrier(); __builtin_amdgcn_sched_barrier(0); }while(0)
#define BAR_ALL()  do{ asm volatile("s_waitcnt vmcnt(0) lgkmcnt(0)" ::: "memory"); \
  __builtin_amdgcn_s_barrier(); __builtin_amdgcn_sched_barrier(0); }while(0)

// ---------------------------------------------------------------------------
// Kernel 0: E[b*SEQ+n][e] = bf16(table[x[b,n]][e]); padding_idx==0 -> zeros.
// ---------------------------------------------------------------------------
__global__ __launch_bounds__(512) void k_embed(const int* __restrict__ x,
                                               const float* __restrict__ tab,
                                               u16* __restrict__ E){
  int r = blockIdx.x * 8 + (threadIdx.x >> 6);   // 0..32767
  int l = threadIdx.x & 63;
  int idx = x[r];
  float4 a = make_float4(0.f,0.f,0.f,0.f), c = a;
  if (idx != 0){
    const float4* src = (const float4*)(tab + (size_t)idx * EMBD);
    a = src[l*2]; c = src[l*2+1];
  }
  bf16x8 v;
  v[0]=f2bf(a.x); v[1]=f2bf(a.y); v[2]=f2bf(a.z); v[3]=f2bf(a.w);
  v[4]=f2bf(c.x); v[5]=f2bf(c.y); v[6]=f2bf(c.z); v[7]=f2bf(c.w);
  *(bf16x8*)(E + (size_t)r * EMBD + l*8) = v;
}

// ---------------------------------------------------------------------------
// Kernel 1: flash attention (Q=K=V=E) + per-Q-tile column max. KVB=32.
// R2-proven dataflow, rebuilt schedule:
//  - Klds double-buffered; STAGE(t+1) at tile top -> full-tile DMA window.
//  - raw s_barrier + lgkmcnt-only waits at B1/B2: DMA never drained mid-tile;
//    single vmcnt(0) at tile top (already complete).
//  - wave (iq=w>>1: 16 q rows, jq=w&1: 16 tokens); Vt wave-private transpose.
// ---------------------------------------------------------------------------
__global__ __launch_bounds__(512, 2) void k_attn(const u16* __restrict__ E,
                                                 float* __restrict__ part){
  __shared__ u16   Klds[2][KVB * EMBD];  // 2 x 32 KB, 16B-chunk swizzled
  __shared__ float Sbuf[QB][36];         // 9.2 KB
  __shared__ u16   Ps[QB][40];           // 5 KB
  __shared__ u16   Vt[8 * 64 * KVB];     // 32 KB: per-wave [64 e][32 tok] swz
  __shared__ float m_lds[QB], l_lds[QB], a_lds[QB];

  const int tid = threadIdx.x;
  const int w   = tid >> 6;              // wave 0..7
  const int l   = tid & 63;
  const int l15 = l & 15, lg = l >> 4;

  // XCD-affine decode: batch b's 32 q-tiles land on XCD (b&7).
  const int blk  = blockIdx.x;
  const int xcd  = blk & 7;
  const int slot = blk >> 3;             // 0..63
  const int b    = xcd + 8 * (slot >> 5);
  const int qt   = slot & 31;
  const size_t ebase = (size_t)b * SEQ * EMBD;

  // ---- Q fragments: wave's 16 q-rows (iq), full D -> 64 VGPR ----
  const int iq = w >> 1, jq = w & 1;
  const u16* qp = E + ebase + (size_t)(qt*QB + iq*16 + l15) * EMBD + lg*8;
  bf16x8 qf[16];
  #pragma unroll
  for (int ks = 0; ks < 16; ks++) qf[ks] = *(const bf16x8*)(qp + ks*32);

  f32x4 acc[4][4];                       // O[ip*16+lg*4+rr][w*64+jp*16+l15]
  #pragma unroll
  for (int ip = 0; ip < 4; ip++)
    #pragma unroll
    for (int jp = 0; jp < 4; jp++) acc[ip][jp] = (f32x4){0.f,0.f,0.f,0.f};

  if (tid < QB){ m_lds[tid] = -INFINITY; l_lds[tid] = 0.f; }

  // stage K tile (32 rows x 1KB) into Klds[tile&1]: wave w -> rows w*4+i.
  // LDS dest lane-linear (base + l*16B); global src chunk pre-swizzled
  // l ^ (row&7) so logical chunk c is stored at c ^ (row&7).
  #define STAGE(tile_)                                                       \
    { const int kk0 = (tile_) * KVB;                                         \
      u16* kd = &Klds[(tile_) & 1][0];                                       \
      _Pragma("unroll")                                                      \
      for (int i = 0; i < 4; i++){                                           \
        const int r = w*4 + i;                                               \
        const u16* src = E + ebase + (size_t)(kk0 + r) * EMBD                \
                           + ((l ^ (r & 7)) * 8);                            \
        gload_lds16(src, kd + (size_t)r * EMBD);                             \
      } }

  STAGE(0)

  const int quad = l & 7, c8 = l >> 3;   // V-load mapping: tok quad*4, e-chunk c8
  const int e7 = l15 & 7;

  for (int t = 0; t < NT; t++){
    const int p  = t & 1;
    const int k0 = t * KVB;

    BAR_ALL();                           // B0: stage(t) landed; bufs reusable

    // ---- issue V row loads for tile t (consumed by transpose below) ----
    bf16x8 vr[4];
    {
      const u16* vp = E + ebase + (size_t)(k0 + quad*4) * EMBD + w*64 + c8*8;
      vr[0] = *(const bf16x8*)(vp);
      vr[1] = *(const bf16x8*)(vp +   EMBD);
      vr[2] = *(const bf16x8*)(vp + 2*EMBD);
      vr[3] = *(const bf16x8*)(vp + 3*EMBD);
    }

    // ---- stage K(t+1) into other buffer: full tile to complete ----
    if (t + 1 < NT) STAGE(t + 1)

    // ---- QK^T: S[iq*16..+16][jq*16..+16] from Klds[p] ----
    f32x4 s0 = (f32x4){0.f,0.f,0.f,0.f};
    {
      const u16* kbase = &Klds[p][(jq*16 + l15) * EMBD];
      __builtin_amdgcn_s_setprio(1);
      #pragma unroll
      for (int ks = 0; ks < 16; ks++){
        const int cst = (ks*4 + lg) ^ e7;
        bf16x8 kb = *(const bf16x8*)(kbase + cst*8);
        s0 = __builtin_amdgcn_mfma_f32_16x16x32_bf16(qf[ks], kb, s0, 0, 0, 0);
      }
      __builtin_amdgcn_s_setprio(0);
    }
    #pragma unroll
    for (int rr = 0; rr < 4; rr++)
      Sbuf[iq*16 + lg*4 + rr][jq*16 + l15] = s0[rr];

    // ---- V transpose into wave-private Vt (compiler emits counted vmcnt
    //      for vr, leaving the 4 stage-DMAs in flight) ----
    #pragma unroll
    for (int i = 0; i < 8; i++){
      const int el = c8*8 + i;                         // e_local 0..63
      const int ch = (quad >> 1) ^ (el & 3);           // swizzled 16B chunk
      short4 sv; sv.x = vr[0][i]; sv.y = vr[1][i];
                 sv.z = vr[2][i]; sv.w = vr[3][i];
      *(short4*)&Vt[(size_t)w*2048 + el*32 + ch*8 + (quad & 1)*4] = sv;
    }

    BAR_LGKM();                          // B1: Sbuf ready (DMA stays in flight)

    // ---- online softmax: 8 threads per q-row, 4 tokens each ----
    {
      const int row = tid >> 3, cg = tid & 7;
      f32x4 sv = *(f32x4*)&Sbuf[row][cg*4];
      float mx = fmaxf(fmaxf(sv[0], sv[1]), fmaxf(sv[2], sv[3]));
      #pragma unroll
      for (int d = 1; d < 8; d <<= 1) mx = fmaxf(mx, __shfl_xor(mx, d));
      const float mold = m_lds[row], lold = l_lds[row];
      const float mnew = fmaxf(mold, mx);
      float p0 = __expf(sv[0] - mnew), p1 = __expf(sv[1] - mnew);
      float p2 = __expf(sv[2] - mnew), p3 = __expf(sv[3] - mnew);
      float sum = (p0 + p1) + (p2 + p3);
      #pragma unroll
      for (int d = 1; d < 8; d <<= 1) sum += __shfl_xor(sum, d);
      const float alpha = __expf(mold - mnew);   // -inf -> 0 on first tile
      if (cg == 0){
        m_lds[row] = mnew;
        l_lds[row] = lold * alpha + sum;
        a_lds[row] = alpha;
      }
      short4 pv; pv.x = f2bf(p0); pv.y = f2bf(p1);
                 pv.z = f2bf(p2); pv.w = f2bf(p3);
      *(short4*)&Ps[row][cg*4] = pv;
    }

    BAR_LGKM();                          // B2: Ps + alpha ready

    // ---- rescale O (skip when all alpha==1), then O += P V ----
    {
      f32x4 al[4];
      int need = 0;
      #pragma unroll
      for (int ip = 0; ip < 4; ip++){
        al[ip] = *(f32x4*)&a_lds[ip*16 + lg*4];
        need |= (al[ip][0] != 1.f) | (al[ip][1] != 1.f) |
                (al[ip][2] != 1.f) | (al[ip][3] != 1.f);
      }
      if (__any(need)){
        #pragma unroll
        for (int ip = 0; ip < 4; ip++)
          #pragma unroll
          for (int jp = 0; jp < 4; jp++)
            #pragma unroll
            for (int rr = 0; rr < 4; rr++) acc[ip][jp][rr] *= al[ip][rr];
      }
    }
    {
      bf16x8 pa[4], vb[4];
      #pragma unroll
      for (int ip = 0; ip < 4; ip++)
        pa[ip] = *(const bf16x8*)&Ps[ip*16 + l15][lg*8];
      #pragma unroll
      for (int jp = 0; jp < 4; jp++){
        const int el = jp*16 + l15;                    // e_local
        const int ch = lg ^ (el & 3);
        vb[jp] = *(const bf16x8*)&Vt[(size_t)w*2048 + el*32 + ch*8];
      }
      __builtin_amdgcn_s_setprio(1);
      #pragma unroll
      for (int ip = 0; ip < 4; ip++)
        #pragma unroll
        for (int jp = 0; jp < 4; jp++)
          acc[ip][jp] = __builtin_amdgcn_mfma_f32_16x16x32_bf16(
                            pa[ip], vb[jp], acc[ip][jp], 0, 0, 0);
      __builtin_amdgcn_s_setprio(0);
    }
  }

  // ---- epilogue: 1/l scaling, column max over 64 q-rows, write partial ----
  // (l_lds final values visible: written before last B2, barrier crossed)
  #pragma unroll
  for (int ip = 0; ip < 4; ip++){
    f32x4 lv = *(f32x4*)&l_lds[ip*16 + lg*4];
    f32x4 inv;
    #pragma unroll
    for (int rr = 0; rr < 4; rr++) inv[rr] = 1.f / lv[rr];
    #pragma unroll
    for (int jp = 0; jp < 4; jp++)
      #pragma unroll
      for (int rr = 0; rr < 4; rr++) acc[ip][jp][rr] *= inv[rr];
  }
  #pragma unroll
  for (int jp = 0; jp < 4; jp++){
    float cm = -INFINITY;
    #pragma unroll
    for (int ip = 0; ip < 4; ip++)
      #pragma unroll
      for (int rr = 0; rr < 4; rr++) cm = fmaxf(cm, acc[ip][jp][rr]);
    cm = fmaxf(cm, __shfl_xor(cm, 16));
    cm = fmaxf(cm, __shfl_xor(cm, 32));
    if (lg == 0)
      part[(size_t)(b*32 + qt) * EMBD + w*64 + jp*16 + l15] = cm;
  }
}

// ---------------------------------------------------------------------------
// Kernel 2: pooled[b][e] = max over 32 q-tiles; out[b][o] = pooled.W[o] + b[o]
// ---------------------------------------------------------------------------
__global__ __launch_bounds__(512) void k_final(const float* __restrict__ part,
                                               const float* __restrict__ Wm,
                                               const float* __restrict__ bias,
                                               float* __restrict__ out){
  __shared__ float pooled[EMBD];
  const int b = blockIdx.x, tid = threadIdx.x;
  float mx = -INFINITY;
  const float* pb = part + (size_t)b * 32 * EMBD + tid;
  #pragma unroll
  for (int qt = 0; qt < 32; qt++) mx = fmaxf(mx, pb[qt * EMBD]);
  pooled[tid] = mx;
  __syncthreads();
  const int w = tid >> 6, l = tid & 63;     // w = output index (8 waves)
  float sum = 0.f;
  #pragma unroll
  for (int m = 0; m < 8; m++)
    sum += pooled[l + m*64] * Wm[w*EMBD + l + m*64];
  #pragma unroll
  for (int d = 1; d < 64; d <<= 1) sum += __shfl_xor(sum, d);
  if (l == 0) out[b * NOUT + w] = sum + bias[w];
}

// ---------------------------------------------------------------------------
extern "C" void kernel_launch(void* const* d_in, const int* in_sizes, int n_in,
                              void* d_out, int out_size, void* d_ws, size_t ws_size,
                              hipStream_t stream){
  const int*   x    = (const int*)  d_in[0];   // [16,2048]
  const float* tab  = (const float*)d_in[1];   // [32000,512]
  const float* Wm   = (const float*)d_in[2];   // [8,512]
  const float* bias = (const float*)d_in[3];   // [8]
  float* out = (float*)d_out;                  // [16,8]

  // ws: E bf16 [16*2048,512] = 32MB, then partials [16][32][512] f32 = 1MB
  u16*   E    = (u16*)d_ws;
  float* part = (float*)((char*)d_ws + (size_t)32 * 1024 * 1024);

  k_embed<<<BATCH*SEQ/8, 512, 0, stream>>>(x, tab, E);
  k_attn <<<BATCH*(SEQ/QB), 512, 0, stream>>>(E, part);
  k_final<<<BATCH, 512, 0, stream>>>(part, Wm, bias, out);
}

// Round 7
// 288.132 us; speedup vs baseline: 1.3353x; 1.3353x over previous
//
#include <hip/hip_runtime.h>

typedef unsigned short u16;
typedef __attribute__((ext_vector_type(8))) short bf16x8;    // 8 bf16 = 4 VGPR
typedef __attribute__((ext_vector_type(4))) float f32x4;
typedef __attribute__((ext_vector_type(16))) float f32x16;

#define BATCH 16
#define SEQ   2048
#define EMBD  512
#define NOUT  8
#define QB    64
#define KVB   64
#define NT    (SEQ/KVB)      // 32 KV tiles

#define GLOBAL_AS __attribute__((address_space(1)))
#define LDS_AS    __attribute__((address_space(3)))

__device__ __forceinline__ u16 f2bf(float f){          // f32 -> bf16 RNE
  unsigned u = __float_as_uint(f);
  u += 0x7fffu + ((u >> 16) & 1u);
  return (u16)(u >> 16);
}
__device__ __forceinline__ float b2f(short s){
  return __uint_as_float(((unsigned)(u16)s) << 16);
}

__device__ __forceinline__ void gload_lds16(const void* g, void* l){
  __builtin_amdgcn_global_load_lds((const GLOBAL_AS unsigned int*)g,
                                   (LDS_AS unsigned int*)l, 16, 0, 0);
}

// ---------------------------------------------------------------------------
// Kernel 0: E[b*SEQ+n][e] = bf16(table[x[b,n]][e]); padding_idx==0 -> zeros.
// ---------------------------------------------------------------------------
__global__ __launch_bounds__(512) void k_embed(const int* __restrict__ x,
                                               const float* __restrict__ tab,
                                               u16* __restrict__ E){
  int r = blockIdx.x * 8 + (threadIdx.x >> 6);   // 0..32767
  int l = threadIdx.x & 63;
  int idx = x[r];
  float4 a = make_float4(0.f,0.f,0.f,0.f), c = a;
  if (idx != 0){
    const float4* src = (const float4*)(tab + (size_t)idx * EMBD);
    a = src[l*2]; c = src[l*2+1];
  }
  bf16x8 v;
  v[0]=f2bf(a.x); v[1]=f2bf(a.y); v[2]=f2bf(a.z); v[3]=f2bf(a.w);
  v[4]=f2bf(c.x); v[5]=f2bf(c.y); v[6]=f2bf(c.z); v[7]=f2bf(c.w);
  *(bf16x8*)(E + (size_t)r * EMBD + l*8) = v;
}

// ---------------------------------------------------------------------------
// Kernel 1: flash attention (Q=K=V=E) + per-Q-tile column max. KVB=64.
// R5 structure, with QK^T moved to 32x32x16 MFMA + e-split:
//  - wave = (iq2=w&1: 32 q rows) x (jq2=(w>>1)&1: 32 toks) x (eh=w>>2: 256 e)
//    -> A-frag covers 32 q rows at 64 VGPR; kb LDS traffic halves (128KB/tile)
//  - partial S (per e-half) written bf16 to Sb2[2][64][72]; softmax sums both
//  - PV unchanged from R5: Ps bf16, wave-private transposed Vt, 16x16 MFMA
//  - 3 x __syncthreads per tile; stage(t+1) after B1; setprio; alpha-skip
// ---------------------------------------------------------------------------
__global__ __launch_bounds__(512, 2) void k_attn(const u16* __restrict__ E,
                                                 float* __restrict__ part){
  __shared__ u16   Klds[KVB * EMBD];     // 64 KB, 16B-chunk swizzled (c^row&7)
  __shared__ u16   Sb2[2][QB][72];       // 18 KB: partial S per e-half, bf16
  __shared__ u16   Ps[QB][72];           // 9.2 KB
  __shared__ u16   Vt[8 * 64 * 64];      // 64 KB: per-wave [64 e][64 tok] swz
  __shared__ float m_lds[QB], l_lds[QB], a_lds[QB];

  const int tid = threadIdx.x;
  const int w   = tid >> 6;              // wave 0..7
  const int l   = tid & 63;
  const int l15 = l & 15, lg = l >> 4;
  const int l31 = l & 31, hi = l >> 5;

  // XCD-affine decode: batch b's 32 q-tiles land on XCD (b&7).
  const int blk  = blockIdx.x;
  const int xcd  = blk & 7;
  const int slot = blk >> 3;             // 0..63
  const int b    = xcd + 8 * (slot >> 5);
  const int qt   = slot & 31;
  const size_t ebase = (size_t)b * SEQ * EMBD;

  // ---- QKT role decode + Q fragments (32 rows x 256 e -> 64 VGPR) ----
  const int iq2 = w & 1, jq2 = (w >> 1) & 1, eh = w >> 2;
  bf16x8 qf[16];
  {
    const u16* qp = E + ebase + (size_t)(qt*QB + iq2*32 + l31) * EMBD
                      + eh*256 + hi*8;
    #pragma unroll
    for (int ks = 0; ks < 16; ks++) qf[ks] = *(const bf16x8*)(qp + ks*16);
  }

  f32x4 acc[4][4];                       // O[ip*16+lg*4+rr][w*64+jp*16+l15]
  #pragma unroll
  for (int ip = 0; ip < 4; ip++)
    #pragma unroll
    for (int jp = 0; jp < 4; jp++) acc[ip][jp] = (f32x4){0.f,0.f,0.f,0.f};

  if (tid < QB){ m_lds[tid] = -INFINITY; l_lds[tid] = 0.f; }

  // stage K rows r=w*8+i; LDS dest wave-uniform base (+lane*16B implicit);
  // global src chunk pre-swizzled l ^ (r&7) so logical chunk c sits at c^(r&7)
  #define STAGE(tile_)                                                       \
    { const int kk0 = (tile_) * KVB;                                         \
      _Pragma("unroll")                                                      \
      for (int i = 0; i < 8; i++){                                           \
        const int r = w*8 + i;                                               \
        const u16* src = E + ebase + (size_t)(kk0 + r) * EMBD                \
                           + ((l ^ (r & 7)) * 8);                            \
        gload_lds16(src, Klds + (size_t)r * EMBD);                           \
      } }

  STAGE(0)

  const int quad = l & 15, c8h = l >> 4;

  for (int t = 0; t < NT; t++){
    const int k0 = t * KVB;
    __syncthreads();                     // B0: stage(t) drained; bufs free

    // ---- issue V row loads (consumed by Vt transpose after QKT) ----
    bf16x8 vr[2][4];
    #pragma unroll
    for (int h = 0; h < 2; h++){
      const int c8 = c8h + h*4;          // e-chunk 0..7 in wave's 64-e slice
      const u16* vp = E + ebase + (size_t)(k0 + quad*4) * EMBD + w*64 + c8*8;
      vr[h][0] = *(const bf16x8*)(vp);
      vr[h][1] = *(const bf16x8*)(vp +   EMBD);
      vr[h][2] = *(const bf16x8*)(vp + 2*EMBD);
      vr[h][3] = *(const bf16x8*)(vp + 3*EMBD);
    }

    // ---- QK^T (32x32x16): partial S[iq2*32..+32][jq2*32..+32] over e-half --
    f32x16 sacc = (f32x16){0.f,0.f,0.f,0.f,0.f,0.f,0.f,0.f,
                           0.f,0.f,0.f,0.f,0.f,0.f,0.f,0.f};
    {
      const int krow = jq2*32 + l31;     // K row (token) for B-frag
      const u16* kbase = &Klds[(size_t)krow * EMBD];
      const int r7 = krow & 7;
      __builtin_amdgcn_s_setprio(1);
      #pragma unroll
      for (int ks = 0; ks < 16; ks++){
        const int c = eh*32 + ks*2 + hi; // 16B chunk within 1KB K row
        bf16x8 kb = *(const bf16x8*)(kbase + ((c ^ r7) * 8));
        sacc = __builtin_amdgcn_mfma_f32_32x32x16_bf16(qf[ks], kb, sacc, 0,0,0);
      }
      __builtin_amdgcn_s_setprio(0);
    }
    // C layout: col=l31 (token), row=(reg&3)+8*(reg>>2)+4*hi
    #pragma unroll
    for (int reg = 0; reg < 16; reg++){
      const int row = iq2*32 + (reg & 3) + 8*(reg >> 2) + 4*hi;
      Sb2[eh][row][jq2*32 + l31] = f2bf(sacc[reg]);
    }

    // ---- V transpose into wave-private Vt (b64 writes, floor-phased) ----
    #pragma unroll
    for (int h = 0; h < 2; h++){
      const int c8 = c8h + h*4;
      #pragma unroll
      for (int i = 0; i < 8; i++){
        const int el = c8*8 + i;                       // e_local 0..63
        const int ch = (quad >> 1) ^ (el & 7);         // swizzled 16B chunk
        short4 sv; sv.x = vr[h][0][i]; sv.y = vr[h][1][i];
                   sv.z = vr[h][2][i]; sv.w = vr[h][3][i];
        *(short4*)&Vt[(size_t)w*4096 + el*64 + ch*8 + (quad&1)*4] = sv;
      }
    }

    __syncthreads();                     // B1: Sb2 + Vt complete

    // ---- stage K(t+1): overlaps softmax + PV, drained at next B0 ----
    if (t + 1 < NT) STAGE(t + 1)

    // ---- online softmax: thread=(row=tid>>3, cg=tid&7); sums both e-halves --
    {
      const int row = tid >> 3, cg = tid & 7;
      bf16x8 a0 = *(const bf16x8*)&Sb2[0][row][cg*8];
      bf16x8 a1 = *(const bf16x8*)&Sb2[1][row][cg*8];
      float sv[8];
      #pragma unroll
      for (int i = 0; i < 8; i++) sv[i] = b2f(a0[i]) + b2f(a1[i]);
      float mx = fmaxf(fmaxf(fmaxf(sv[0],sv[1]), fmaxf(sv[2],sv[3])),
                       fmaxf(fmaxf(sv[4],sv[5]), fmaxf(sv[6],sv[7])));
      #pragma unroll
      for (int d = 1; d < 8; d <<= 1) mx = fmaxf(mx, __shfl_xor(mx, d));
      const float mold = m_lds[row], lold = l_lds[row];
      const float mnew = fmaxf(mold, mx);
      float pp[8];
      #pragma unroll
      for (int i = 0; i < 8; i++) pp[i] = __expf(sv[i] - mnew);
      float sum = ((pp[0]+pp[1])+(pp[2]+pp[3])) + ((pp[4]+pp[5])+(pp[6]+pp[7]));
      #pragma unroll
      for (int d = 1; d < 8; d <<= 1) sum += __shfl_xor(sum, d);
      const float alpha = __expf(mold - mnew);   // -inf -> 0 on first tile
      if (cg == 0){
        m_lds[row] = mnew;
        l_lds[row] = lold * alpha + sum;
        a_lds[row] = alpha;
      }
      bf16x8 pv;
      #pragma unroll
      for (int i = 0; i < 8; i++) pv[i] = (short)f2bf(pp[i]);
      *(bf16x8*)&Ps[row][cg*8] = pv;
    }

    __syncthreads();                     // B2: Ps + alpha ready

    // ---- rescale O (skip when all alpha==1), then O += P V ----
    {
      f32x4 al[4];
      int need = 0;
      #pragma unroll
      for (int ip = 0; ip < 4; ip++){
        al[ip] = *(f32x4*)&a_lds[ip*16 + lg*4];
        need |= (al[ip][0] != 1.f) | (al[ip][1] != 1.f) |
                (al[ip][2] != 1.f) | (al[ip][3] != 1.f);
      }
      if (__any(need)){
        #pragma unroll
        for (int ip = 0; ip < 4; ip++)
          #pragma unroll
          for (int jp = 0; jp < 4; jp++)
            #pragma unroll
            for (int rr = 0; rr < 4; rr++) acc[ip][jp][rr] *= al[ip][rr];
      }
    }
    #pragma unroll
    for (int kt = 0; kt < 2; kt++){
      bf16x8 pa[4], vb[4];
      #pragma unroll
      for (int ip = 0; ip < 4; ip++)
        pa[ip] = *(const bf16x8*)&Ps[ip*16 + l15][kt*32 + lg*8];
      #pragma unroll
      for (int jp = 0; jp < 4; jp++){
        const int el = jp*16 + l15;                    // e_local
        const int ch = (kt*4 + lg) ^ (el & 7);
        vb[jp] = *(const bf16x8*)&Vt[(size_t)w*4096 + el*64 + ch*8];
      }
      __builtin_amdgcn_s_setprio(1);
      #pragma unroll
      for (int ip = 0; ip < 4; ip++)
        #pragma unroll
        for (int jp = 0; jp < 4; jp++)
          acc[ip][jp] = __builtin_amdgcn_mfma_f32_16x16x32_bf16(
                            pa[ip], vb[jp], acc[ip][jp], 0, 0, 0);
      __builtin_amdgcn_s_setprio(0);
    }
  }

  __syncthreads();
  // ---- epilogue: 1/l scaling, column max over 64 q-rows, write partial ----
  #pragma unroll
  for (int ip = 0; ip < 4; ip++){
    f32x4 lv = *(f32x4*)&l_lds[ip*16 + lg*4];
    f32x4 inv;
    #pragma unroll
    for (int rr = 0; rr < 4; rr++) inv[rr] = 1.f / lv[rr];
    #pragma unroll
    for (int jp = 0; jp < 4; jp++)
      #pragma unroll
      for (int rr = 0; rr < 4; rr++) acc[ip][jp][rr] *= inv[rr];
  }
  #pragma unroll
  for (int jp = 0; jp < 4; jp++){
    float cm = -INFINITY;
    #pragma unroll
    for (int ip = 0; ip < 4; ip++)
      #pragma unroll
      for (int rr = 0; rr < 4; rr++) cm = fmaxf(cm, acc[ip][jp][rr]);
    cm = fmaxf(cm, __shfl_xor(cm, 16));
    cm = fmaxf(cm, __shfl_xor(cm, 32));
    if (lg == 0)
      part[(size_t)(b*32 + qt) * EMBD + w*64 + jp*16 + l15] = cm;
  }
}

// ---------------------------------------------------------------------------
// Kernel 2: pooled[b][e] = max over 32 q-tiles; out[b][o] = pooled.W[o] + b[o]
// ---------------------------------------------------------------------------
__global__ __launch_bounds__(512) void k_final(const float* __restrict__ part,
                                               const float* __restrict__ Wm,
                                               const float* __restrict__ bias,
                                               float* __restrict__ out){
  __shared__ float pooled[EMBD];
  const int b = blockIdx.x, tid = threadIdx.x;
  float mx = -INFINITY;
  const float* pb = part + (size_t)b * 32 * EMBD + tid;
  #pragma unroll
  for (int qt = 0; qt < 32; qt++) mx = fmaxf(mx, pb[qt * EMBD]);
  pooled[tid] = mx;
  __syncthreads();
  const int w = tid >> 6, l = tid & 63;     // w = output index (8 waves)
  float sum = 0.f;
  #pragma unroll
  for (int m = 0; m < 8; m++)
    sum += pooled[l + m*64] * Wm[w*EMBD + l + m*64];
  #pragma unroll
  for (int d = 1; d < 64; d <<= 1) sum += __shfl_xor(sum, d);
  if (l == 0) out[b * NOUT + w] = sum + bias[w];
}

// ---------------------------------------------------------------------------
extern "C" void kernel_launch(void* const* d_in, const int* in_sizes, int n_in,
                              void* d_out, int out_size, void* d_ws, size_t ws_size,
                              hipStream_t stream){
  const int*   x    = (const int*)  d_in[0];   // [16,2048]
  const float* tab  = (const float*)d_in[1];   // [32000,512]
  const float* Wm   = (const float*)d_in[2];   // [8,512]
  const float* bias = (const float*)d_in[3];   // [8]
  float* out = (float*)d_out;                  // [16,8]

  // ws: E bf16 [16*2048,512] = 32MB, then partials [16][32][512] f32 = 1MB
  u16*   E    = (u16*)d_ws;
  float* part = (float*)((char*)d_ws + (size_t)32 * 1024 * 1024);

  k_embed<<<BATCH*SEQ/8, 512, 0, stream>>>(x, tab, E);
  k_attn <<<BATCH*(SEQ/QB), 512, 0, stream>>>(E, part);
  k_final<<<BATCH, 512, 0, stream>>>(part, Wm, bias, out);
}